// Round 8
// baseline (983.988 us; speedup 1.0000x reference)
//
#include <hip/hip_runtime.h>
#include <math.h>

typedef _Float16 half8 __attribute__((ext_vector_type(8)));
typedef _Float16 half4v __attribute__((ext_vector_type(4)));
typedef float f32x4 __attribute__((ext_vector_type(4)));

#define LOG2E 1.44269504f

// ---- global_load_lds helpers: per-lane global src, wave-uniform LDS dst (+lane*size) ----
// Only HW-verified widths used: 16B (m97) and 4B (m03). 12B caused the r19 failure.
typedef __attribute__((address_space(1))) const unsigned int gas_u32;
typedef __attribute__((address_space(3))) unsigned int las_u32;

__device__ __forceinline__ void gll4(const void* gsrc, void* ldst) {
  __builtin_amdgcn_global_load_lds((gas_u32*)gsrc, (las_u32*)ldst, 4, 0, 0);
}

// ---------------- merged prep: all 5 weight packs + 3 downsamples, one dispatch ------------
__device__ __forceinline__ void pack_generic(int rem, int NT, int COUT, float scale,
                                             const float* __restrict__ src,
                                             _Float16* __restrict__ dst) {
  int j = rem & 7, lane = (rem >> 3) & 63, rest = rem >> 9;
  int t = rest % NT, s = rest / NT;
  int oc = t * 16 + (lane & 15);
  int tap = s >> 1;
  int ic = (s & 1) * 32 + ((lane >> 4) & 3) * 8 + j;
  float v = (oc < COUT) ? src[((size_t)oc * 64 + ic) * 9 + tap] * scale : 0.f;
  dst[rem] = (_Float16)v;
}

__global__ void prep_all_kernel(const float* __restrict__ fWa, const float* __restrict__ fWb,
                                const float* __restrict__ fWc, const float* __restrict__ W2a,
                                const float* __restrict__ W2b, const float* __restrict__ x,
                                _Float16* __restrict__ Bp1, _Float16* __restrict__ BpA,
                                _Float16* __restrict__ BpB, _Float16* __restrict__ Bpb,
                                _Float16* __restrict__ Bpc,
                                _Float16* __restrict__ s1, _Float16* __restrict__ s2,
                                _Float16* __restrict__ s3) {
  int idx = blockIdx.x * blockDim.x + threadIdx.x;
  if (idx < 184320) {                       // Bpb: 5 scales x 18x4x512
    int sc = idx / 36864, rem = idx - sc * 36864;
    pack_generic(rem, 4, 64, 1.f, fWb + sc * 36864, Bpb + sc * 36864);
  } else if (idx < 460800) {                // Bpc: 5 scales x 18x6x512, prescaled by log2e
    int i2 = idx - 184320;
    int sc = i2 / 55296, rem = i2 - sc * 55296;
    pack_generic(rem, 6, 81, LOG2E, fWc + sc * 46656, Bpc + sc * 55296);
  } else if (idx < 471040) {                // Bp1: conv1, K=9 pad 32
    int i2 = idx - 460800;
    int sc = i2 >> 11, rem = i2 & 2047;
    int j = rem & 7, lane = (rem >> 3) & 63, nt = rem >> 9;
    int oc = nt * 16 + (lane & 15);
    int k = ((lane >> 4) & 3) * 8 + j;
    float v = (k < 9) ? fWa[sc * 576 + oc * 9 + k] : 0.f;
    Bp1[sc * 2048 + rem] = (_Float16)v;
  } else if (idx < 475136) {                // BpA: tail stage1, K=45 pad 64
    int rem = idx - 471040;
    int j = rem & 7, lane = (rem >> 3) & 63;
    int nt = (rem >> 9) & 3, s = rem >> 11;
    int oc = nt * 16 + (lane & 15);
    int k = s * 32 + ((lane >> 4) & 3) * 8 + j;
    float v = 0.f;
    if (k < 45) { int ic = k / 9, tap = k - ic * 9; v = W2a[(oc * 5 + ic) * 9 + tap]; }
    BpA[rem] = (_Float16)v;
  } else if (idx < 484352) {                // BpB: tail stage2 (COUT=1, NT=1)
    pack_generic(idx - 475136, 1, 1, 1.f, W2b, BpB);
  } else if (idx < 615424) {                // s1: 512->256, both batches
    int i2 = idx - 484352;
    int n = i2 >> 16, p = i2 & 65535, rr = p >> 8, cc = p & 255;
    s1[i2] = (_Float16)x[(size_t)n * 262144 + (size_t)(rr * 2) * 512 + cc * 2];
  } else if (idx < 648192) {                // s2: 512->128
    int i2 = idx - 615424;
    int n = i2 >> 14, p = i2 & 16383, rr = p >> 7, cc = p & 127;
    s2[i2] = (_Float16)x[(size_t)n * 262144 + (size_t)(rr * 4) * 512 + cc * 4];
  } else if (idx < 656384) {                // s3: 512->64
    int i2 = idx - 648192;
    int n = i2 >> 12, p = i2 & 4095, rr = p >> 6, cc = p & 63;
    s3[i2] = (_Float16)x[(size_t)n * 262144 + (size_t)(rr * 8) * 512 + cc * 8];
  }
}

// ---------------- block -> (scale, batch, tile) mapping, all 5 scales in one grid ----------
__device__ __forceinline__ int xcd_swizzle(int bid) {
  return (bid & 7) * 596 + (bid >> 3);     // 4768 = 8 * 596
}

__device__ __forceinline__ void map_block(int bid, int& sc, int& n, int& bx, int& by,
                                          int& Hs, int& RS) {
  if (bid < 2048) { sc = 0; Hs = 512; RS = 1;
    int t = bid; n = t >> 10; t &= 1023; by = t >> 5; bx = t & 31; }
  else if (bid < 4096) { sc = 4; Hs = 512; RS = 1;
    int t = bid - 2048; n = t >> 10; t &= 1023; by = t >> 5; bx = t & 31; }
  else if (bid < 4608) { sc = 1; Hs = 256; RS = 2;
    int t = bid - 4096; n = t >> 8; t &= 255; by = t >> 4; bx = t & 15; }
  else if (bid < 4736) { sc = 2; Hs = 128; RS = 4;
    int t = bid - 4608; n = t >> 6; t &= 63; by = t >> 3; bx = t & 7; }
  else { sc = 3; Hs = 64; RS = 8;
    int t = bid - 4736; n = t >> 4; t &= 15; by = t >> 2; bx = t & 3; }
}

__device__ __forceinline__ const void* pick_src(int sc, const float* x, const float* g,
                                                const _Float16* s1, const _Float16* s2,
                                                const _Float16* s3, int& sStr, bool& f16s) {
  if (sc == 0) { sStr = 262144; f16s = false; return x; }
  if (sc == 1) { sStr = 65536; f16s = true; return s1; }
  if (sc == 2) { sStr = 16384; f16s = true; return s2; }
  if (sc == 3) { sStr = 4096; f16s = true; return s3; }
  sStr = 262144; f16s = false; return g;
}

__device__ __forceinline__ float src_load(const void* p, bool f16s, size_t off) {
  return f16s ? (float)((const _Float16*)p)[off] : ((const float*)p)[off];
}

// ============ r20/r21 counted-vmcnt tap loop (T3/T4/T5, proven on conv3sd) ================
// slab layout: [px = R*18+C][64 ch], 8 slots of 8 ch; physical slot = logical^(C&7).
// B packed s-major (s = tap*2 + half); Bsd double buffer, per buf NT*1024 halves.
template <int NT>
__device__ __forceinline__ void stageB_tap(const half8* __restrict__ Bp,
                                           _Float16* __restrict__ Bsd,
                                           int t, int buf, int tid) {
  const int lane = tid & 63, wv = tid >> 6;
  const char* s = (const char*)(Bp + (size_t)t * NT * 128) + wv * NT * 256 + lane * 4;
  char* d = (char*)Bsd + (size_t)buf * NT * 2048 + wv * NT * 256;
#pragma unroll
  for (int i = 0; i < NT; ++i) gll4(s + i * 256, d + i * 256);
}

template <int NT>
__device__ __forceinline__ void stageB01(const half8* __restrict__ Bp,
                                         _Float16* __restrict__ Bsd, int tid) {
  stageB_tap<NT>(Bp, Bsd, 0, 0, tid);
  stageB_tap<NT>(Bp, Bsd, 1, 1, tid);
}

template <int MT, int NT, bool SWAP>
__device__ __forceinline__ void tap_loop_counted(const _Float16* __restrict__ slab,
                                                 const half8* __restrict__ Bp,
                                                 _Float16* __restrict__ Bsd,
                                                 f32x4 (&acc)[MT][NT], int tid) {
  const int lane = tid & 63;
  const int wv = tid >> 6;
  const int quad = lane >> 4;
  const int ln15 = lane & 15;
  auto tap_body = [&](int t, int buf) {
    const int dy = t / 3, dx = t - dy * 3;
    const int C = dx + ln15;
    const int cx = C & 7;
    const _Float16* bb = Bsd + (size_t)buf * NT * 1024;
#pragma unroll
    for (int h = 0; h < 2; ++h) {
      half8 bf[NT];
#pragma unroll
      for (int nt = 0; nt < NT; ++nt)
        bf[nt] = *(const half8*)(bb + h * NT * 512 + (nt * 64 + lane) * 8);
      half8 af[MT];
#pragma unroll
      for (int mt = 0; mt < MT; ++mt) {
        const int px = (wv * MT + mt + dy) * 18 + C;
        af[mt] = *(const half8*)(slab + (size_t)px * 64 + ((h * 4 + quad) ^ cx) * 8);
      }
      __builtin_amdgcn_s_setprio(1);
#pragma unroll
      for (int mt = 0; mt < MT; ++mt)
#pragma unroll
        for (int nt = 0; nt < NT; ++nt)
          acc[mt][nt] = SWAP
            ? __builtin_amdgcn_mfma_f32_16x16x32_f16(bf[nt], af[mt], acc[mt][nt], 0, 0, 0)
            : __builtin_amdgcn_mfma_f32_16x16x32_f16(af[mt], bf[nt], acc[mt][nt], 0, 0, 0);
      __builtin_amdgcn_s_setprio(0);
    }
  };
#pragma unroll 1
  for (int t = 0; t < 8; ++t) {
    if (t >= 1) stageB_tap<NT>(Bp, Bsd, t + 1, (t + 1) & 1, tid);  // buf safe: BAR_b(t-1)
    asm volatile("s_waitcnt vmcnt(%0)" :: "n"(NT) : "memory");     // B(t) landed; B(t+1) flies
    __builtin_amdgcn_s_barrier();                                  // BAR_a
    asm volatile("" ::: "memory");
    tap_body(t, t & 1);
    asm volatile("s_waitcnt lgkmcnt(0)" ::: "memory");             // my buf reads retired
    __builtin_amdgcn_s_barrier();                                  // BAR_b
    asm volatile("" ::: "memory");
  }
  asm volatile("s_waitcnt vmcnt(0)" ::: "memory");
  __builtin_amdgcn_s_barrier();
  asm volatile("" ::: "memory");
  tap_body(8, 0);
}

// K-loop + global-store epilogue for the tail's stage-2 (unswapped).
template <int MT, int NT, int COUT, int COUTP, bool RELU, typename OutT>
__device__ __forceinline__ void mfma_body(const _Float16* slab, const half8* __restrict__ Bp,
                                          _Float16* __restrict__ Bsd,
                                          const float* __restrict__ bias,
                                          OutT* __restrict__ out,
                                          int H, int W, int gr0, int gc0, int tid) {
  f32x4 acc[MT][NT];
  const f32x4 zz = {0.f, 0.f, 0.f, 0.f};
#pragma unroll
  for (int mt = 0; mt < MT; ++mt)
#pragma unroll
    for (int nt = 0; nt < NT; ++nt) acc[mt][nt] = zz;
  tap_loop_counted<MT, NT, false>(slab, Bp, Bsd, acc, tid);
  const int lane = tid & 63;
  const int wv = tid >> 6;
  const int quad = lane >> 4;
  const int ln15 = lane & 15;
  float bvv[NT];
#pragma unroll
  for (int nt = 0; nt < NT; ++nt) {
    const int oc = nt * 16 + ln15;
    bvv[nt] = (oc < COUT) ? bias[oc] : 0.f;
  }
#pragma unroll
  for (int mt = 0; mt < MT; ++mt) {
    const int gr = gr0 + wv * MT + mt;
#pragma unroll
    for (int reg = 0; reg < 4; ++reg) {
      const int gc = gc0 + quad * 4 + reg;
#pragma unroll
      for (int nt = 0; nt < NT; ++nt) {
        const int oc = nt * 16 + ln15;
        float v = acc[mt][nt][reg] + bvv[nt];
        if (RELU) v = fmaxf(v, 0.f);
        if (oc < COUTP) out[((size_t)gr * W + gc) * COUTP + oc] = (OutT)v;
      }
    }
  }
}

// ================= r23: fused conv1+conv2+conv3, channel-split for 2 blocks/CU =============
// r22 diagnosis: fusion killed traffic (FETCH 80->3.5MB) but LDS 95KB -> 1 block/CU removed
// co-residency; per-block wall latency was fully exposed (538us). r23 splits conv1/conv2
// over 32-ch halves: slabAh = 20x20x32 (25.6KB), conv2 accumulates each half's 9 taps
// (K=32 MFMA; B-pack's s=tap*2+half layout matches) into persistent regs a2s[3][4], then
// writes slabB once. LDS: xs 2304 + slabAh 25600 + slabB 41472 = 69376B -> 2 blocks/CU.
__global__ __launch_bounds__(512, 2)
void fused_ms_kernel(const float* __restrict__ x, const float* __restrict__ g,
                     const _Float16* __restrict__ s1, const _Float16* __restrict__ s2,
                     const _Float16* __restrict__ s3,
                     const half8* __restrict__ Bp1b, const float* __restrict__ fba,
                     const half8* __restrict__ Bpbb, const float* __restrict__ fbb,
                     const half8* __restrict__ Bpcb, const float* __restrict__ fbc,
                     float* __restrict__ cat) {
  __shared__ float xs[24 * 24];
  __shared__ __align__(16) _Float16 slabAh[400 * 32];   // 25600 B (conv1 half-out, 20x20x32)
  __shared__ __align__(16) _Float16 slabB[324 * 64];    // 41472 B (conv2 out, 18x18x64)
  _Float16* Bsd = slabAh;                               // conv3 B dbuf aliases dead slabAh

  int sc, n, bx, by, Hs, RS;
  map_block(xcd_swizzle(blockIdx.x), sc, n, bx, by, Hs, RS);
  int sStr; bool f16s;
  const void* src = pick_src(sc, x, g, s1, s2, s3, sStr, f16s);
  const half8* Bp1 = Bp1b + sc * 256;
  const half8* Bpb = Bpbb + sc * 4608;
  const half8* Bpc = Bpcb + sc * 6912;
  const float* ba = fba + sc * 64;
  const float* bb = fbb + sc * 64;
  const float* bias = fbc + sc * 81;
  float* catp = cat + (size_t)(sc * 2 + n) * 262144;
  const int H = Hs, W = Hs;
  const int tid = threadIdx.x;
  const int gr0 = by * 16, gc0 = bx * 16;
  const int lane = tid & 63;
  const int wv = tid >> 6;
  const int quad = lane >> 4;
  const int ln15 = lane & 15;

  // ---- P0: xs (24x24, halo 4) — serves conv1 input AND the dynconv epilogue ----
  for (int i = tid; i < 576; i += 512) {
    int R = i / 24, C = i % 24;
    int gr = gr0 - 4 + R, gc = gc0 - 4 + C;
    xs[i] = (gr >= 0 && gr < H && gc >= 0 && gc < W)
                ? src_load(src, f16s, (size_t)n * sStr + (size_t)gr * W + gc) : 0.f;
  }
  __syncthreads();

  // conv1/conv2 constants (held across both half-passes)
  half8 bf1[4];
  float b1v[4][4], b2v[4][4];
#pragma unroll
  for (int nt = 0; nt < 4; ++nt) {
    bf1[nt] = Bp1[nt * 64 + lane];
#pragma unroll
    for (int reg = 0; reg < 4; ++reg) {
      b1v[nt][reg] = ba[nt * 16 + quad * 4 + reg];
      b2v[nt][reg] = bb[nt * 16 + quad * 4 + reg];
    }
  }
  int off1[8];
  bool v1[8];
#pragma unroll
  for (int j = 0; j < 8; ++j) {
    int k = quad * 8 + j;
    v1[j] = (k < 9);
    off1[j] = v1[j] ? ((k / 3) * 24 + (k % 3)) : 0;
  }
  const f32x4 zz = {0.f, 0.f, 0.f, 0.f};
  f32x4 a2s[3][4];                                     // persistent conv2 accumulators
#pragma unroll
  for (int ti = 0; ti < 3; ++ti)
#pragma unroll
    for (int nt = 0; nt < 4; ++nt) a2s[ti][nt] = zz;

#pragma unroll 1
  for (int hh = 0; hh < 2; ++hh) {
    // ---- P1(hh): conv1 half -> slabAh (400 px x 32 ch; slot = logical^(CA&3)) ----
#pragma unroll 1
    for (int mt = wv; mt < 25; mt += 8) {
      int p = mt * 16 + ln15;                          // 0..399, all valid
      int RA = p / 20, CA = p - RA * 20;
      int base = (RA + 1) * 24 + (CA + 1);
      half8 af;
#pragma unroll
      for (int j = 0; j < 8; ++j)
        af[j] = v1[j] ? (_Float16)xs[base + off1[j]] : (_Float16)0.f;
      f32x4 a1[2] = {zz, zz};
#pragma unroll
      for (int nt2 = 0; nt2 < 2; ++nt2)
        a1[nt2] = __builtin_amdgcn_mfma_f32_16x16x32_f16(bf1[hh * 2 + nt2], af, a1[nt2], 0, 0, 0);
      int gr = gr0 - 2 + RA, gc = gc0 - 2 + CA;
      bool inb = (gr >= 0 && gr < H && gc >= 0 && gc < W);
      _Float16* sb = slabAh + (size_t)p * 32 + (quad & 1) * 4;
      const int csw = CA & 3;
#pragma unroll
      for (int nt2 = 0; nt2 < 2; ++nt2) {
        half4v w;
#pragma unroll
        for (int reg = 0; reg < 4; ++reg) {
          float v = inb ? fmaxf(a1[nt2][reg] + b1v[hh * 2 + nt2][reg], 0.f) : 0.f;
          w[reg] = (_Float16)v;
        }
        const int chunk = nt2 * 2 + (quad >> 1);
        *(half4v*)(sb + ((chunk ^ csw) * 8)) = w;
      }
    }
    __syncthreads();                                   // slabAh(hh) ready

    // ---- P2(hh): conv2 partial — 9 taps x K=32, accumulate into a2s ----
#pragma unroll 1
    for (int ti = 0; ti < 3; ++ti) {
      int mt = wv + ti * 8;
      if (mt >= 21) break;
      int p = mt * 16 + ln15;
      int pcl = (p < 323) ? p : 323;
      int R3 = pcl / 18, C3 = pcl - R3 * 18;
      auto step = [&](int tap, half8 (&bf)[4]) {
        const int dy = tap / 3, dx = tap - dy * 3;
        const int CA2 = C3 + dx;
        const int pA = (R3 + dy) * 20 + CA2;
        half8 af = *(const half8*)(slabAh + (size_t)pA * 32 + ((quad ^ (CA2 & 3)) * 8));
#pragma unroll
        for (int nt = 0; nt < 4; ++nt)
          a2s[ti][nt] = __builtin_amdgcn_mfma_f32_16x16x32_f16(bf[nt], af, a2s[ti][nt], 0, 0, 0);
      };
      half8 bA[4], bB[4];
#pragma unroll
      for (int nt = 0; nt < 4; ++nt) bA[nt] = Bpb[(size_t)(hh * 4 + nt) * 64 + lane]; // tap0
#pragma unroll 1
      for (int i = 0; i < 4; ++i) {
        const int t1 = 2 * i + 1;
        const int t2 = (2 * i + 2 < 9) ? 2 * i + 2 : 8;
#pragma unroll
        for (int nt = 0; nt < 4; ++nt)
          bB[nt] = Bpb[(size_t)((t1 * 2 + hh) * 4 + nt) * 64 + lane];
        step(2 * i, bA);
#pragma unroll
        for (int nt = 0; nt < 4; ++nt)
          bA[nt] = Bpb[(size_t)((t2 * 2 + hh) * 4 + nt) * 64 + lane];
        step(t1, bB);
      }
      step(8, bA);
    }
    __syncthreads();                                   // slabAh reusable / done
  }

  // ---- write slabB (bias + relu; conv3's proven [px][64] swizzled layout) ----
#pragma unroll 1
  for (int ti = 0; ti < 3; ++ti) {
    int mt = wv + ti * 8;
    if (mt >= 21) break;
    int p = mt * 16 + ln15;
    if (p < 324) {
      int R3 = p / 18, C3 = p - R3 * 18;
      int gr = gr0 - 1 + R3, gc = gc0 - 1 + C3;
      bool inb = (gr >= 0 && gr < H && gc >= 0 && gc < W);
      _Float16* sb = slabB + (size_t)p * 64 + (quad & 1) * 4;
      const int csw = C3 & 7;
#pragma unroll
      for (int nt = 0; nt < 4; ++nt) {
        half4v w;
#pragma unroll
        for (int reg = 0; reg < 4; ++reg) {
          float v = inb ? fmaxf(a2s[ti][nt][reg] + b2v[nt][reg], 0.f) : 0.f;
          w[reg] = (_Float16)v;
        }
        const int chunk = nt * 2 + (quad >> 1);
        *(half4v*)(sb + ((chunk ^ csw) * 8)) = w;
      }
    }
  }
  __syncthreads();            // slabB ready; drains all VMEM (ledger clean); slabAh dead

  // ---- P3: conv3 counted tap loop (r20-proven) + softmax/dynconv epilogue ----
  stageB01<6>(Bpc, Bsd, tid);                          // Bsd aliases slabAh
  f32x4 acc[2][6];
#pragma unroll
  for (int mt = 0; mt < 2; ++mt)
#pragma unroll
    for (int nt = 0; nt < 6; ++nt) acc[mt][nt] = zz;
  tap_loop_counted<2, 6, true>(slabB, Bpc, Bsd, acc, tid);

  float bvv[6][4];
  int dyx[6][4];
  bool vv[6][4];
#pragma unroll
  for (int nt = 0; nt < 6; ++nt)
#pragma unroll
    for (int reg = 0; reg < 4; ++reg) {
      int ch = nt * 16 + quad * 4 + reg;
      bool ok = (ch < 81);
      vv[nt][reg] = ok;
      bvv[nt][reg] = ok ? bias[ch] * LOG2E : 0.f;
      int dy = ch / 9, dx = ch - dy * 9;
      dyx[nt][reg] = ok ? dy * 24 + dx : 0;
    }
  const int lrs = (RS == 2) ? 1 : ((RS == 4) ? 2 : 3);
#pragma unroll
  for (int mt = 0; mt < 2; ++mt) {
    const float* xb = xs + (wv * 2 + mt) * 24 + ln15;
    float sum = 0.f, y = 0.f;
#pragma unroll
    for (int nt = 0; nt < 6; ++nt)
#pragma unroll
      for (int reg = 0; reg < 4; ++reg) {
        if (vv[nt][reg]) {
          float e = exp2f(acc[mt][nt][reg] + bvv[nt][reg]);
          sum += e;
          y = fmaf(e, xb[dyx[nt][reg]], y);
        }
      }
    sum += __shfl_xor(sum, 16, 64);
    sum += __shfl_xor(sum, 32, 64);
    y += __shfl_xor(y, 16, 64);
    y += __shfl_xor(y, 32, 64);
    const float o = y / sum;
    const int gr = gr0 + wv * 2 + mt, gc = gc0 + ln15;
    if (RS == 1) {
      if (quad == 0) catp[(size_t)gr * 512 + gc] = o;
    } else {
      for (int t = quad; t < RS * RS; t += 4) {
        int a = t >> lrs, b = t & (RS - 1);
        catp[((size_t)(gr * RS + a)) * 512 + (gc * RS + b)] = o;
      }
    }
  }
}

// ---------------- fused tail: cat(5 planes) -> MFMA 5->64 relu (LDS) -> MFMA 64->1 ---------
__global__ __launch_bounds__(512, 4)
void tail_fused_kernel(const float* __restrict__ cat,
                       const half8* __restrict__ BpA, const float* __restrict__ b2a,
                       const half8* __restrict__ BpB, const float* __restrict__ b2b,
                       float* __restrict__ out) {
  __shared__ float cs[20 * 20 * 5];                      // first: gather clamps stay inside
  __shared__ __align__(16) _Float16 hid[18 * 18 * 64];
  __shared__ __align__(16) _Float16 BsS[2 * 1024];       // 4 KB B double-buffer (NT=1)
  const int n = blockIdx.z;
  float* op = out + (size_t)n * (512 * 512);
  const int tid = threadIdx.x;
  const int gr0 = blockIdx.y * 16, gc0 = blockIdx.x * 16;
  stageB01<1>(BpB, BsS, tid);           // issue early; drained by the pre-stage2 __syncthreads
  for (int i = tid; i < 2000; i += 512) {
    int ic = i / 400, px = i - ic * 400;
    int R = px / 20, C = px - R * 20;
    int gr = gr0 - 2 + R, gc = gc0 - 2 + C;
    cs[px * 5 + ic] = (gr >= 0 && gr < 512 && gc >= 0 && gc < 512)
                ? cat[(size_t)(ic * 2 + n) * 262144 + (size_t)gr * 512 + gc] : 0.f;
  }
  __syncthreads();
  const int lane = tid & 63;
  const int wv = tid >> 6;
  const int quad = lane >> 4;
  const int ln15 = lane & 15;
  int goff[2][8];
  bool gok[2][8];
#pragma unroll
  for (int s = 0; s < 2; ++s)
#pragma unroll
    for (int j = 0; j < 8; ++j) {
      int k = s * 32 + quad * 8 + j;
      bool ok = (k < 45);
      int ic = k / 9;
      int tap = k - ic * 9;
      int dy = tap / 3, dx = tap - dy * 3;
      goff[s][j] = ok ? ((dy * 20 + dx) * 5 + ic) : 0;
      gok[s][j] = ok;
    }
  half8 bfA[2][4];
  float bAv[4][4];
#pragma unroll
  for (int s = 0; s < 2; ++s)
#pragma unroll
    for (int nt = 0; nt < 4; ++nt) bfA[s][nt] = BpA[(s * 4 + nt) * 64 + lane];
#pragma unroll
  for (int nt = 0; nt < 4; ++nt)
#pragma unroll
    for (int reg = 0; reg < 4; ++reg) bAv[nt][reg] = b2a[nt * 16 + quad * 4 + reg];
  const f32x4 zz = {0.f, 0.f, 0.f, 0.f};
#pragma unroll 1
  for (int mt = wv; mt < 21; mt += 8) {
    int p = mt * 16 + ln15;
    int pcl = (p < 323) ? p : 323;
    int base = (pcl / 18) * 100 + (pcl % 18) * 5;
    f32x4 acc1[4] = {zz, zz, zz, zz};
#pragma unroll
    for (int s = 0; s < 2; ++s) {
      half8 af;
#pragma unroll
      for (int j = 0; j < 8; ++j) {
        float a = gok[s][j] ? cs[base + goff[s][j]] : 0.f;
        af[j] = (_Float16)a;
      }
#pragma unroll
      for (int nt = 0; nt < 4; ++nt)
        acc1[nt] = __builtin_amdgcn_mfma_f32_16x16x32_f16(bfA[s][nt], af, acc1[nt], 0, 0, 0);
    }
    if (p < 324) {
      int R2 = p / 18, C2 = p - R2 * 18;
      int gr = gr0 - 1 + R2, gc = gc0 - 1 + C2;
      bool inb = (gr >= 0 && gr < 512 && gc >= 0 && gc < 512);
      _Float16* sb = hid + p * 64 + (quad & 1) * 4;
      const int csw = C2 & 7;
#pragma unroll
      for (int nt = 0; nt < 4; ++nt) {
        half4v w;
#pragma unroll
        for (int reg = 0; reg < 4; ++reg) {
          float v = inb ? fmaxf(acc1[nt][reg] + bAv[nt][reg], 0.f) : 0.f;
          w[reg] = (_Float16)v;
        }
        const int chunk = nt * 2 + (quad >> 1);
        *(half4v*)(sb + ((chunk ^ csw) * 8)) = w;
      }
    }
  }
  __syncthreads();                      // hid ready; drains vmcnt (B0/B1 landed long ago)
  mfma_body<2, 1, 1, 1, false, float>(hid, BpB, BsS, b2b, op, 512, 512, gr0, gc0, tid);
}

extern "C" void kernel_launch(void* const* d_in, const int* in_sizes, int n_in,
                              void* d_out, int out_size, void* d_ws, size_t ws_size,
                              hipStream_t stream) {
  (void)in_sizes; (void)n_in; (void)out_size; (void)ws_size;
  const float* x   = (const float*)d_in[0];
  const float* g   = (const float*)d_in[1];
  const float* fWa = (const float*)d_in[2];
  const float* fba = (const float*)d_in[3];
  const float* fWb = (const float*)d_in[4];
  const float* fbb = (const float*)d_in[5];
  const float* fWc = (const float*)d_in[6];
  const float* fbc = (const float*)d_in[7];
  const float* W2a = (const float*)d_in[8];
  const float* b2a = (const float*)d_in[9];
  const float* W2b = (const float*)d_in[10];
  const float* b2b = (const float*)d_in[11];
  float* out = (float*)d_out;
  float* ws = (float*)d_ws;

  // carve (float units) — h2 region unused since r22 (fusion killed the round-trip)
  float* Bp1F = ws;                     // 5120
  float* BpAF = Bp1F + 5120;            // 2048
  float* BpBF = BpAF + 2048;            // 4608
  float* BpbF = BpBF + 4608;            // 92160
  float* BpcF = BpbF + 92160;           // 138240
  float* s1F  = BpcF + 138240;          // 65536
  float* s2F  = s1F + 65536;            // 16384
  float* s3F  = s2F + 16384;            // 4096
  float* cat  = s3F + 4096;             // 2621440 (10 planes of 262144)
  _Float16* s1 = (_Float16*)s1F;
  _Float16* s2 = (_Float16*)s2F;
  _Float16* s3 = (_Float16*)s3F;
  const half8* Bp1 = (const half8*)Bp1F;
  const half8* BpA = (const half8*)BpAF;
  const half8* BpB = (const half8*)BpBF;
  const half8* Bpb = (const half8*)BpbF;
  const half8* Bpc = (const half8*)BpcF;

  prep_all_kernel<<<2564, 256, 0, stream>>>(fWa, fWb, fWc, W2a, W2b, x,
                                            (_Float16*)Bp1F, (_Float16*)BpAF,
                                            (_Float16*)BpBF, (_Float16*)BpbF,
                                            (_Float16*)BpcF, s1, s2, s3);
  fused_ms_kernel<<<4768, 512, 0, stream>>>(x, g, s1, s2, s3, Bp1, fba, Bpb, fbb,
                                            Bpc, fbc, cat);
  tail_fused_kernel<<<dim3(32, 32, 2), 512, 0, stream>>>(cat, BpA, b2a, BpB, b2b, out);
}

// Round 9
// 739.354 us; speedup vs baseline: 1.3309x; 1.3309x over previous
//
#include <hip/hip_runtime.h>
#include <math.h>

typedef _Float16 half8 __attribute__((ext_vector_type(8)));
typedef _Float16 half4v __attribute__((ext_vector_type(4)));
typedef float f32x4 __attribute__((ext_vector_type(4)));

#define LOG2E 1.44269504f

// ---- global_load_lds helpers: per-lane global src, wave-uniform LDS dst (+lane*size) ----
// Only HW-verified widths used: 16B (m97) and 4B (m03). 12B caused the r19 failure.
typedef __attribute__((address_space(1))) const unsigned int gas_u32;
typedef __attribute__((address_space(3))) unsigned int las_u32;

__device__ __forceinline__ void gll4(const void* gsrc, void* ldst) {
  __builtin_amdgcn_global_load_lds((gas_u32*)gsrc, (las_u32*)ldst, 4, 0, 0);
}

// ---------------- merged prep: all 5 weight packs + 3 downsamples, one dispatch ------------
__device__ __forceinline__ void pack_generic(int rem, int NT, int COUT, float scale,
                                             const float* __restrict__ src,
                                             _Float16* __restrict__ dst) {
  int j = rem & 7, lane = (rem >> 3) & 63, rest = rem >> 9;
  int t = rest % NT, s = rest / NT;
  int oc = t * 16 + (lane & 15);
  int tap = s >> 1;
  int ic = (s & 1) * 32 + ((lane >> 4) & 3) * 8 + j;
  float v = (oc < COUT) ? src[((size_t)oc * 64 + ic) * 9 + tap] * scale : 0.f;
  dst[rem] = (_Float16)v;
}

__global__ void prep_all_kernel(const float* __restrict__ fWa, const float* __restrict__ fWb,
                                const float* __restrict__ fWc, const float* __restrict__ W2a,
                                const float* __restrict__ W2b, const float* __restrict__ x,
                                _Float16* __restrict__ Bp1, _Float16* __restrict__ BpA,
                                _Float16* __restrict__ BpB, _Float16* __restrict__ Bpb,
                                _Float16* __restrict__ Bpc,
                                _Float16* __restrict__ s1, _Float16* __restrict__ s2,
                                _Float16* __restrict__ s3) {
  int idx = blockIdx.x * blockDim.x + threadIdx.x;
  if (idx < 184320) {                       // Bpb: 5 scales x 18x4x512
    int sc = idx / 36864, rem = idx - sc * 36864;
    pack_generic(rem, 4, 64, 1.f, fWb + sc * 36864, Bpb + sc * 36864);
  } else if (idx < 460800) {                // Bpc: 5 scales x 18x6x512, prescaled by log2e
    int i2 = idx - 184320;
    int sc = i2 / 55296, rem = i2 - sc * 55296;
    pack_generic(rem, 6, 81, LOG2E, fWc + sc * 46656, Bpc + sc * 55296);
  } else if (idx < 471040) {                // Bp1: conv1, K=9 pad 32
    int i2 = idx - 460800;
    int sc = i2 >> 11, rem = i2 & 2047;
    int j = rem & 7, lane = (rem >> 3) & 63, nt = rem >> 9;
    int oc = nt * 16 + (lane & 15);
    int k = ((lane >> 4) & 3) * 8 + j;
    float v = (k < 9) ? fWa[sc * 576 + oc * 9 + k] : 0.f;
    Bp1[sc * 2048 + rem] = (_Float16)v;
  } else if (idx < 475136) {                // BpA: tail stage1, K=45 pad 64
    int rem = idx - 471040;
    int j = rem & 7, lane = (rem >> 3) & 63;
    int nt = (rem >> 9) & 3, s = rem >> 11;
    int oc = nt * 16 + (lane & 15);
    int k = s * 32 + ((lane >> 4) & 3) * 8 + j;
    float v = 0.f;
    if (k < 45) { int ic = k / 9, tap = k - ic * 9; v = W2a[(oc * 5 + ic) * 9 + tap]; }
    BpA[rem] = (_Float16)v;
  } else if (idx < 484352) {                // BpB: tail stage2 (COUT=1, NT=1)
    pack_generic(idx - 475136, 1, 1, 1.f, W2b, BpB);
  } else if (idx < 615424) {                // s1: 512->256, both batches
    int i2 = idx - 484352;
    int n = i2 >> 16, p = i2 & 65535, rr = p >> 8, cc = p & 255;
    s1[i2] = (_Float16)x[(size_t)n * 262144 + (size_t)(rr * 2) * 512 + cc * 2];
  } else if (idx < 648192) {                // s2: 512->128
    int i2 = idx - 615424;
    int n = i2 >> 14, p = i2 & 16383, rr = p >> 7, cc = p & 127;
    s2[i2] = (_Float16)x[(size_t)n * 262144 + (size_t)(rr * 4) * 512 + cc * 4];
  } else if (idx < 656384) {                // s3: 512->64
    int i2 = idx - 648192;
    int n = i2 >> 12, p = i2 & 4095, rr = p >> 6, cc = p & 63;
    s3[i2] = (_Float16)x[(size_t)n * 262144 + (size_t)(rr * 8) * 512 + cc * 8];
  }
}

// ---------------- block -> (scale, batch, tile) mapping, all 5 scales in one grid ----------
__device__ __forceinline__ int xcd_swizzle(int bid) {
  return (bid & 7) * 596 + (bid >> 3);     // 4768 = 8 * 596
}

__device__ __forceinline__ void map_block(int bid, int& sc, int& n, int& bx, int& by,
                                          int& Hs, int& RS) {
  if (bid < 2048) { sc = 0; Hs = 512; RS = 1;
    int t = bid; n = t >> 10; t &= 1023; by = t >> 5; bx = t & 31; }
  else if (bid < 4096) { sc = 4; Hs = 512; RS = 1;
    int t = bid - 2048; n = t >> 10; t &= 1023; by = t >> 5; bx = t & 31; }
  else if (bid < 4608) { sc = 1; Hs = 256; RS = 2;
    int t = bid - 4096; n = t >> 8; t &= 255; by = t >> 4; bx = t & 15; }
  else if (bid < 4736) { sc = 2; Hs = 128; RS = 4;
    int t = bid - 4608; n = t >> 6; t &= 63; by = t >> 3; bx = t & 7; }
  else { sc = 3; Hs = 64; RS = 8;
    int t = bid - 4736; n = t >> 4; t &= 15; by = t >> 2; bx = t & 3; }
}

__device__ __forceinline__ const void* pick_src(int sc, const float* x, const float* g,
                                                const _Float16* s1, const _Float16* s2,
                                                const _Float16* s3, int& sStr, bool& f16s) {
  if (sc == 0) { sStr = 262144; f16s = false; return x; }
  if (sc == 1) { sStr = 65536; f16s = true; return s1; }
  if (sc == 2) { sStr = 16384; f16s = true; return s2; }
  if (sc == 3) { sStr = 4096; f16s = true; return s3; }
  sStr = 262144; f16s = false; return g;
}

__device__ __forceinline__ float src_load(const void* p, bool f16s, size_t off) {
  return f16s ? (float)((const _Float16*)p)[off] : ((const float*)p)[off];
}

// ============ r20/r21 counted-vmcnt tap loop (T3/T4/T5, proven on conv3sd) ================
// slab layout: [px = R*18+C][64 ch], 8 slots of 8 ch; physical slot = logical^(C&7).
// B packed s-major (s = tap*2 + half); Bsd double buffer, per buf NT*1024 halves.
template <int NT>
__device__ __forceinline__ void stageB_tap(const half8* __restrict__ Bp,
                                           _Float16* __restrict__ Bsd,
                                           int t, int buf, int tid) {
  const int lane = tid & 63, wv = tid >> 6;
  const char* s = (const char*)(Bp + (size_t)t * NT * 128) + wv * NT * 256 + lane * 4;
  char* d = (char*)Bsd + (size_t)buf * NT * 2048 + wv * NT * 256;
#pragma unroll
  for (int i = 0; i < NT; ++i) gll4(s + i * 256, d + i * 256);
}

template <int NT>
__device__ __forceinline__ void stageB01(const half8* __restrict__ Bp,
                                         _Float16* __restrict__ Bsd, int tid) {
  stageB_tap<NT>(Bp, Bsd, 0, 0, tid);
  stageB_tap<NT>(Bp, Bsd, 1, 1, tid);
}

template <int MT, int NT, bool SWAP>
__device__ __forceinline__ void tap_loop_counted(const _Float16* __restrict__ slab,
                                                 const half8* __restrict__ Bp,
                                                 _Float16* __restrict__ Bsd,
                                                 f32x4 (&acc)[MT][NT], int tid) {
  const int lane = tid & 63;
  const int wv = tid >> 6;
  const int quad = lane >> 4;
  const int ln15 = lane & 15;
  auto tap_body = [&](int t, int buf) {
    const int dy = t / 3, dx = t - dy * 3;
    const int C = dx + ln15;
    const int cx = C & 7;
    const _Float16* bb = Bsd + (size_t)buf * NT * 1024;
#pragma unroll
    for (int h = 0; h < 2; ++h) {
      half8 bf[NT];
#pragma unroll
      for (int nt = 0; nt < NT; ++nt)
        bf[nt] = *(const half8*)(bb + h * NT * 512 + (nt * 64 + lane) * 8);
      half8 af[MT];
#pragma unroll
      for (int mt = 0; mt < MT; ++mt) {
        const int px = (wv * MT + mt + dy) * 18 + C;
        af[mt] = *(const half8*)(slab + (size_t)px * 64 + ((h * 4 + quad) ^ cx) * 8);
      }
      __builtin_amdgcn_s_setprio(1);
#pragma unroll
      for (int mt = 0; mt < MT; ++mt)
#pragma unroll
        for (int nt = 0; nt < NT; ++nt)
          acc[mt][nt] = SWAP
            ? __builtin_amdgcn_mfma_f32_16x16x32_f16(bf[nt], af[mt], acc[mt][nt], 0, 0, 0)
            : __builtin_amdgcn_mfma_f32_16x16x32_f16(af[mt], bf[nt], acc[mt][nt], 0, 0, 0);
      __builtin_amdgcn_s_setprio(0);
    }
  };
#pragma unroll 1
  for (int t = 0; t < 8; ++t) {
    if (t >= 1) stageB_tap<NT>(Bp, Bsd, t + 1, (t + 1) & 1, tid);  // buf safe: BAR_b(t-1)
    asm volatile("s_waitcnt vmcnt(%0)" :: "n"(NT) : "memory");     // B(t) landed; B(t+1) flies
    __builtin_amdgcn_s_barrier();                                  // BAR_a
    asm volatile("" ::: "memory");
    tap_body(t, t & 1);
    asm volatile("s_waitcnt lgkmcnt(0)" ::: "memory");             // my buf reads retired
    __builtin_amdgcn_s_barrier();                                  // BAR_b
    asm volatile("" ::: "memory");
  }
  asm volatile("s_waitcnt vmcnt(0)" ::: "memory");
  __builtin_amdgcn_s_barrier();
  asm volatile("" ::: "memory");
  tap_body(8, 0);
}

// K-loop + global-store epilogue for the tail's stage-2 (unswapped).
template <int MT, int NT, int COUT, int COUTP, bool RELU, typename OutT>
__device__ __forceinline__ void mfma_body(const _Float16* slab, const half8* __restrict__ Bp,
                                          _Float16* __restrict__ Bsd,
                                          const float* __restrict__ bias,
                                          OutT* __restrict__ out,
                                          int H, int W, int gr0, int gc0, int tid) {
  f32x4 acc[MT][NT];
  const f32x4 zz = {0.f, 0.f, 0.f, 0.f};
#pragma unroll
  for (int mt = 0; mt < MT; ++mt)
#pragma unroll
    for (int nt = 0; nt < NT; ++nt) acc[mt][nt] = zz;
  tap_loop_counted<MT, NT, false>(slab, Bp, Bsd, acc, tid);
  const int lane = tid & 63;
  const int wv = tid >> 6;
  const int quad = lane >> 4;
  const int ln15 = lane & 15;
  float bvv[NT];
#pragma unroll
  for (int nt = 0; nt < NT; ++nt) {
    const int oc = nt * 16 + ln15;
    bvv[nt] = (oc < COUT) ? bias[oc] : 0.f;
  }
#pragma unroll
  for (int mt = 0; mt < MT; ++mt) {
    const int gr = gr0 + wv * MT + mt;
#pragma unroll
    for (int reg = 0; reg < 4; ++reg) {
      const int gc = gc0 + quad * 4 + reg;
#pragma unroll
      for (int nt = 0; nt < NT; ++nt) {
        const int oc = nt * 16 + ln15;
        float v = acc[mt][nt][reg] + bvv[nt];
        if (RELU) v = fmaxf(v, 0.f);
        if (oc < COUTP) out[((size_t)gr * W + gc) * COUTP + oc] = (OutT)v;
      }
    }
  }
}

// ================= r24: fused conv1+conv2+conv3, channel-split, STATIC acc indexing ========
// r23's 933us was rule #20: `#pragma unroll 1` ti-loops made a2s[ti] runtime-indexed ->
// scratch allocation -> 2.3GB of localMem HBM traffic (WRITE_SIZE 1.57GB, VGPR dropped to
// 64). r24 fully unrolls the ti loops (break -> guard) so a2s lives in VGPRs. Design
// otherwise identical: slabAh 20x20x32 half-slab, conv2 accumulates both halves' 9 taps
// into persistent regs, slabB written once; LDS 69376B -> 2 blocks/CU.
__global__ __launch_bounds__(512, 2)
void fused_ms_kernel(const float* __restrict__ x, const float* __restrict__ g,
                     const _Float16* __restrict__ s1, const _Float16* __restrict__ s2,
                     const _Float16* __restrict__ s3,
                     const half8* __restrict__ Bp1b, const float* __restrict__ fba,
                     const half8* __restrict__ Bpbb, const float* __restrict__ fbb,
                     const half8* __restrict__ Bpcb, const float* __restrict__ fbc,
                     float* __restrict__ cat) {
  __shared__ float xs[24 * 24];
  __shared__ __align__(16) _Float16 slabAh[400 * 32];   // 25600 B (conv1 half-out, 20x20x32)
  __shared__ __align__(16) _Float16 slabB[324 * 64];    // 41472 B (conv2 out, 18x18x64)
  _Float16* Bsd = slabAh;                               // conv3 B dbuf aliases dead slabAh

  int sc, n, bx, by, Hs, RS;
  map_block(xcd_swizzle(blockIdx.x), sc, n, bx, by, Hs, RS);
  int sStr; bool f16s;
  const void* src = pick_src(sc, x, g, s1, s2, s3, sStr, f16s);
  const half8* Bp1 = Bp1b + sc * 256;
  const half8* Bpb = Bpbb + sc * 4608;
  const half8* Bpc = Bpcb + sc * 6912;
  const float* ba = fba + sc * 64;
  const float* bb = fbb + sc * 64;
  const float* bias = fbc + sc * 81;
  float* catp = cat + (size_t)(sc * 2 + n) * 262144;
  const int H = Hs, W = Hs;
  const int tid = threadIdx.x;
  const int gr0 = by * 16, gc0 = bx * 16;
  const int lane = tid & 63;
  const int wv = tid >> 6;
  const int quad = lane >> 4;
  const int ln15 = lane & 15;

  // ---- P0: xs (24x24, halo 4) — serves conv1 input AND the dynconv epilogue ----
  for (int i = tid; i < 576; i += 512) {
    int R = i / 24, C = i % 24;
    int gr = gr0 - 4 + R, gc = gc0 - 4 + C;
    xs[i] = (gr >= 0 && gr < H && gc >= 0 && gc < W)
                ? src_load(src, f16s, (size_t)n * sStr + (size_t)gr * W + gc) : 0.f;
  }
  __syncthreads();

  // conv1/conv2 constants (held across both half-passes)
  half8 bf1[4];
  float b1v[4][4], b2v[4][4];
#pragma unroll
  for (int nt = 0; nt < 4; ++nt) {
    bf1[nt] = Bp1[nt * 64 + lane];
#pragma unroll
    for (int reg = 0; reg < 4; ++reg) {
      b1v[nt][reg] = ba[nt * 16 + quad * 4 + reg];
      b2v[nt][reg] = bb[nt * 16 + quad * 4 + reg];
    }
  }
  int off1[8];
  bool v1[8];
#pragma unroll
  for (int j = 0; j < 8; ++j) {
    int k = quad * 8 + j;
    v1[j] = (k < 9);
    off1[j] = v1[j] ? ((k / 3) * 24 + (k % 3)) : 0;
  }
  const f32x4 zz = {0.f, 0.f, 0.f, 0.f};
  f32x4 a2s[3][4];                                     // persistent conv2 accumulators (VGPR)
#pragma unroll
  for (int ti = 0; ti < 3; ++ti)
#pragma unroll
    for (int nt = 0; nt < 4; ++nt) a2s[ti][nt] = zz;

#pragma unroll 1
  for (int hh = 0; hh < 2; ++hh) {
    // ---- P1(hh): conv1 half -> slabAh (400 px x 32 ch; slot = logical^(CA&3)) ----
#pragma unroll 1
    for (int mt = wv; mt < 25; mt += 8) {
      int p = mt * 16 + ln15;                          // 0..399, all valid
      int RA = p / 20, CA = p - RA * 20;
      int base = (RA + 1) * 24 + (CA + 1);
      half8 af;
#pragma unroll
      for (int j = 0; j < 8; ++j)
        af[j] = v1[j] ? (_Float16)xs[base + off1[j]] : (_Float16)0.f;
      f32x4 a1[2] = {zz, zz};
#pragma unroll
      for (int nt2 = 0; nt2 < 2; ++nt2)
        a1[nt2] = __builtin_amdgcn_mfma_f32_16x16x32_f16(bf1[hh * 2 + nt2], af, a1[nt2], 0, 0, 0);
      int gr = gr0 - 2 + RA, gc = gc0 - 2 + CA;
      bool inb = (gr >= 0 && gr < H && gc >= 0 && gc < W);
      _Float16* sb = slabAh + (size_t)p * 32 + (quad & 1) * 4;
      const int csw = CA & 3;
#pragma unroll
      for (int nt2 = 0; nt2 < 2; ++nt2) {
        half4v w;
#pragma unroll
        for (int reg = 0; reg < 4; ++reg) {
          float v = inb ? fmaxf(a1[nt2][reg] + b1v[hh * 2 + nt2][reg], 0.f) : 0.f;
          w[reg] = (_Float16)v;
        }
        const int chunk = nt2 * 2 + (quad >> 1);
        *(half4v*)(sb + ((chunk ^ csw) * 8)) = w;
      }
    }
    __syncthreads();                                   // slabAh(hh) ready

    // ---- P2(hh): conv2 partial — 9 taps x K=32, accumulate into a2s (STATIC ti) ----
#pragma unroll
    for (int ti = 0; ti < 3; ++ti) {
      const int mt = wv + ti * 8;
      if (mt < 21) {
        int p = mt * 16 + ln15;
        int pcl = (p < 323) ? p : 323;
        int R3 = pcl / 18, C3 = pcl - R3 * 18;
        auto step = [&](int tap, half8 (&bf)[4]) {
          const int dy = tap / 3, dx = tap - dy * 3;
          const int CA2 = C3 + dx;
          const int pA = (R3 + dy) * 20 + CA2;
          half8 af = *(const half8*)(slabAh + (size_t)pA * 32 + ((quad ^ (CA2 & 3)) * 8));
#pragma unroll
          for (int nt = 0; nt < 4; ++nt)
            a2s[ti][nt] = __builtin_amdgcn_mfma_f32_16x16x32_f16(bf[nt], af, a2s[ti][nt], 0, 0, 0);
        };
        half8 bA[4], bB[4];
#pragma unroll
        for (int nt = 0; nt < 4; ++nt) bA[nt] = Bpb[(size_t)(hh * 4 + nt) * 64 + lane]; // tap0
#pragma unroll 1
        for (int i = 0; i < 4; ++i) {
          const int t1 = 2 * i + 1;
          const int t2 = (2 * i + 2 < 9) ? 2 * i + 2 : 8;
#pragma unroll
          for (int nt = 0; nt < 4; ++nt)
            bB[nt] = Bpb[(size_t)((t1 * 2 + hh) * 4 + nt) * 64 + lane];
          step(2 * i, bA);
#pragma unroll
          for (int nt = 0; nt < 4; ++nt)
            bA[nt] = Bpb[(size_t)((t2 * 2 + hh) * 4 + nt) * 64 + lane];
          step(t1, bB);
        }
        step(8, bA);
      }
    }
    __syncthreads();                                   // slabAh reusable / done
  }

  // ---- write slabB (bias + relu; conv3's proven [px][64] swizzled layout; STATIC ti) ----
#pragma unroll
  for (int ti = 0; ti < 3; ++ti) {
    const int mt = wv + ti * 8;
    if (mt < 21) {
      int p = mt * 16 + ln15;
      if (p < 324) {
        int R3 = p / 18, C3 = p - R3 * 18;
        int gr = gr0 - 1 + R3, gc = gc0 - 1 + C3;
        bool inb = (gr >= 0 && gr < H && gc >= 0 && gc < W);
        _Float16* sb = slabB + (size_t)p * 64 + (quad & 1) * 4;
        const int csw = C3 & 7;
#pragma unroll
        for (int nt = 0; nt < 4; ++nt) {
          half4v w;
#pragma unroll
          for (int reg = 0; reg < 4; ++reg) {
            float v = inb ? fmaxf(a2s[ti][nt][reg] + b2v[nt][reg], 0.f) : 0.f;
            w[reg] = (_Float16)v;
          }
          const int chunk = nt * 2 + (quad >> 1);
          *(half4v*)(sb + ((chunk ^ csw) * 8)) = w;
        }
      }
    }
  }
  __syncthreads();            // slabB ready; drains all VMEM (ledger clean); slabAh dead

  // ---- P3: conv3 counted tap loop (r20-proven) + softmax/dynconv epilogue ----
  stageB01<6>(Bpc, Bsd, tid);                          // Bsd aliases slabAh
  f32x4 acc[2][6];
#pragma unroll
  for (int mt = 0; mt < 2; ++mt)
#pragma unroll
    for (int nt = 0; nt < 6; ++nt) acc[mt][nt] = zz;
  tap_loop_counted<2, 6, true>(slabB, Bpc, Bsd, acc, tid);

  float bvv[6][4];
  int dyx[6][4];
  bool vv[6][4];
#pragma unroll
  for (int nt = 0; nt < 6; ++nt)
#pragma unroll
    for (int reg = 0; reg < 4; ++reg) {
      int ch = nt * 16 + quad * 4 + reg;
      bool ok = (ch < 81);
      vv[nt][reg] = ok;
      bvv[nt][reg] = ok ? bias[ch] * LOG2E : 0.f;
      int dy = ch / 9, dx = ch - dy * 9;
      dyx[nt][reg] = ok ? dy * 24 + dx : 0;
    }
  const int lrs = (RS == 2) ? 1 : ((RS == 4) ? 2 : 3);
#pragma unroll
  for (int mt = 0; mt < 2; ++mt) {
    const float* xb = xs + (wv * 2 + mt) * 24 + ln15;
    float sum = 0.f, y = 0.f;
#pragma unroll
    for (int nt = 0; nt < 6; ++nt)
#pragma unroll
      for (int reg = 0; reg < 4; ++reg) {
        if (vv[nt][reg]) {
          float e = exp2f(acc[mt][nt][reg] + bvv[nt][reg]);
          sum += e;
          y = fmaf(e, xb[dyx[nt][reg]], y);
        }
      }
    sum += __shfl_xor(sum, 16, 64);
    sum += __shfl_xor(sum, 32, 64);
    y += __shfl_xor(y, 16, 64);
    y += __shfl_xor(y, 32, 64);
    const float o = y / sum;
    const int gr = gr0 + wv * 2 + mt, gc = gc0 + ln15;
    if (RS == 1) {
      if (quad == 0) catp[(size_t)gr * 512 + gc] = o;
    } else {
      for (int t = quad; t < RS * RS; t += 4) {
        int a = t >> lrs, b = t & (RS - 1);
        catp[((size_t)(gr * RS + a)) * 512 + (gc * RS + b)] = o;
      }
    }
  }
}

// ---------------- fused tail: cat(5 planes) -> MFMA 5->64 relu (LDS) -> MFMA 64->1 ---------
__global__ __launch_bounds__(512, 4)
void tail_fused_kernel(const float* __restrict__ cat,
                       const half8* __restrict__ BpA, const float* __restrict__ b2a,
                       const half8* __restrict__ BpB, const float* __restrict__ b2b,
                       float* __restrict__ out) {
  __shared__ float cs[20 * 20 * 5];                      // first: gather clamps stay inside
  __shared__ __align__(16) _Float16 hid[18 * 18 * 64];
  __shared__ __align__(16) _Float16 BsS[2 * 1024];       // 4 KB B double-buffer (NT=1)
  const int n = blockIdx.z;
  float* op = out + (size_t)n * (512 * 512);
  const int tid = threadIdx.x;
  const int gr0 = blockIdx.y * 16, gc0 = blockIdx.x * 16;
  stageB01<1>(BpB, BsS, tid);           // issue early; drained by the pre-stage2 __syncthreads
  for (int i = tid; i < 2000; i += 512) {
    int ic = i / 400, px = i - ic * 400;
    int R = px / 20, C = px - R * 20;
    int gr = gr0 - 2 + R, gc = gc0 - 2 + C;
    cs[px * 5 + ic] = (gr >= 0 && gr < 512 && gc >= 0 && gc < 512)
                ? cat[(size_t)(ic * 2 + n) * 262144 + (size_t)gr * 512 + gc] : 0.f;
  }
  __syncthreads();
  const int lane = tid & 63;
  const int wv = tid >> 6;
  const int quad = lane >> 4;
  const int ln15 = lane & 15;
  int goff[2][8];
  bool gok[2][8];
#pragma unroll
  for (int s = 0; s < 2; ++s)
#pragma unroll
    for (int j = 0; j < 8; ++j) {
      int k = s * 32 + quad * 8 + j;
      bool ok = (k < 45);
      int ic = k / 9;
      int tap = k - ic * 9;
      int dy = tap / 3, dx = tap - dy * 3;
      goff[s][j] = ok ? ((dy * 20 + dx) * 5 + ic) : 0;
      gok[s][j] = ok;
    }
  half8 bfA[2][4];
  float bAv[4][4];
#pragma unroll
  for (int s = 0; s < 2; ++s)
#pragma unroll
    for (int nt = 0; nt < 4; ++nt) bfA[s][nt] = BpA[(s * 4 + nt) * 64 + lane];
#pragma unroll
  for (int nt = 0; nt < 4; ++nt)
#pragma unroll
    for (int reg = 0; reg < 4; ++reg) bAv[nt][reg] = b2a[nt * 16 + quad * 4 + reg];
  const f32x4 zz = {0.f, 0.f, 0.f, 0.f};
#pragma unroll 1
  for (int mt = wv; mt < 21; mt += 8) {
    int p = mt * 16 + ln15;
    int pcl = (p < 323) ? p : 323;
    int base = (pcl / 18) * 100 + (pcl % 18) * 5;
    f32x4 acc1[4] = {zz, zz, zz, zz};
#pragma unroll
    for (int s = 0; s < 2; ++s) {
      half8 af;
#pragma unroll
      for (int j = 0; j < 8; ++j) {
        float a = gok[s][j] ? cs[base + goff[s][j]] : 0.f;
        af[j] = (_Float16)a;
      }
#pragma unroll
      for (int nt = 0; nt < 4; ++nt)
        acc1[nt] = __builtin_amdgcn_mfma_f32_16x16x32_f16(bfA[s][nt], af, acc1[nt], 0, 0, 0);
    }
    if (p < 324) {
      int R2 = p / 18, C2 = p - R2 * 18;
      int gr = gr0 - 1 + R2, gc = gc0 - 1 + C2;
      bool inb = (gr >= 0 && gr < 512 && gc >= 0 && gc < 512);
      _Float16* sb = hid + p * 64 + (quad & 1) * 4;
      const int csw = C2 & 7;
#pragma unroll
      for (int nt = 0; nt < 4; ++nt) {
        half4v w;
#pragma unroll
        for (int reg = 0; reg < 4; ++reg) {
          float v = inb ? fmaxf(acc1[nt][reg] + bAv[nt][reg], 0.f) : 0.f;
          w[reg] = (_Float16)v;
        }
        const int chunk = nt * 2 + (quad >> 1);
        *(half4v*)(sb + ((chunk ^ csw) * 8)) = w;
      }
    }
  }
  __syncthreads();                      // hid ready; drains vmcnt (B0/B1 landed long ago)
  mfma_body<2, 1, 1, 1, false, float>(hid, BpB, BsS, b2b, op, 512, 512, gr0, gc0, tid);
}

extern "C" void kernel_launch(void* const* d_in, const int* in_sizes, int n_in,
                              void* d_out, int out_size, void* d_ws, size_t ws_size,
                              hipStream_t stream) {
  (void)in_sizes; (void)n_in; (void)out_size; (void)ws_size;
  const float* x   = (const float*)d_in[0];
  const float* g   = (const float*)d_in[1];
  const float* fWa = (const float*)d_in[2];
  const float* fba = (const float*)d_in[3];
  const float* fWb = (const float*)d_in[4];
  const float* fbb = (const float*)d_in[5];
  const float* fWc = (const float*)d_in[6];
  const float* fbc = (const float*)d_in[7];
  const float* W2a = (const float*)d_in[8];
  const float* b2a = (const float*)d_in[9];
  const float* W2b = (const float*)d_in[10];
  const float* b2b = (const float*)d_in[11];
  float* out = (float*)d_out;
  float* ws = (float*)d_ws;

  // carve (float units) — h2 region unused since r22 (fusion killed the round-trip)
  float* Bp1F = ws;                     // 5120
  float* BpAF = Bp1F + 5120;            // 2048
  float* BpBF = BpAF + 2048;            // 4608
  float* BpbF = BpBF + 4608;            // 92160
  float* BpcF = BpbF + 92160;           // 138240
  float* s1F  = BpcF + 138240;          // 65536
  float* s2F  = s1F + 65536;            // 16384
  float* s3F  = s2F + 16384;            // 4096
  float* cat  = s3F + 4096;             // 2621440 (10 planes of 262144)
  _Float16* s1 = (_Float16*)s1F;
  _Float16* s2 = (_Float16*)s2F;
  _Float16* s3 = (_Float16*)s3F;
  const half8* Bp1 = (const half8*)Bp1F;
  const half8* BpA = (const half8*)BpAF;
  const half8* BpB = (const half8*)BpBF;
  const half8* Bpb = (const half8*)BpbF;
  const half8* Bpc = (const half8*)BpcF;

  prep_all_kernel<<<2564, 256, 0, stream>>>(fWa, fWb, fWc, W2a, W2b, x,
                                            (_Float16*)Bp1F, (_Float16*)BpAF,
                                            (_Float16*)BpBF, (_Float16*)BpbF,
                                            (_Float16*)BpcF, s1, s2, s3);
  fused_ms_kernel<<<4768, 512, 0, stream>>>(x, g, s1, s2, s3, Bp1, fba, Bpb, fbb,
                                            Bpc, fbc, cat);
  tail_fused_kernel<<<dim3(32, 32, 2), 512, 0, stream>>>(cat, BpA, b2a, BpB, b2b, out);
}

// Round 10
// 376.842 us; speedup vs baseline: 2.6111x; 1.9620x over previous
//
#include <hip/hip_runtime.h>
#include <math.h>

typedef _Float16 half8 __attribute__((ext_vector_type(8)));
typedef _Float16 half4v __attribute__((ext_vector_type(4)));
typedef float f32x4 __attribute__((ext_vector_type(4)));

#define LOG2E 1.44269504f

// ---- global_load_lds helpers: per-lane global src, wave-uniform LDS dst (+lane*size) ----
// Only HW-verified widths used: 16B (m97) and 4B (m03). 12B caused the r19 failure.
typedef __attribute__((address_space(1))) const unsigned int gas_u32;
typedef __attribute__((address_space(3))) unsigned int las_u32;

__device__ __forceinline__ void gll16(const void* gsrc, void* ldst) {
  __builtin_amdgcn_global_load_lds((gas_u32*)gsrc, (las_u32*)ldst, 16, 0, 0);
}
__device__ __forceinline__ void gll4(const void* gsrc, void* ldst) {
  __builtin_amdgcn_global_load_lds((gas_u32*)gsrc, (las_u32*)ldst, 4, 0, 0);
}

// ---------------- merged prep: all 5 weight packs + 3 downsamples, one dispatch ------------
__device__ __forceinline__ void pack_generic(int rem, int NT, int COUT, float scale,
                                             const float* __restrict__ src,
                                             _Float16* __restrict__ dst) {
  int j = rem & 7, lane = (rem >> 3) & 63, rest = rem >> 9;
  int t = rest % NT, s = rest / NT;
  int oc = t * 16 + (lane & 15);
  int tap = s >> 1;
  int ic = (s & 1) * 32 + ((lane >> 4) & 3) * 8 + j;
  float v = (oc < COUT) ? src[((size_t)oc * 64 + ic) * 9 + tap] * scale : 0.f;
  dst[rem] = (_Float16)v;
}

__global__ void prep_all_kernel(const float* __restrict__ fWa, const float* __restrict__ fWb,
                                const float* __restrict__ fWc, const float* __restrict__ W2a,
                                const float* __restrict__ W2b, const float* __restrict__ x,
                                _Float16* __restrict__ Bp1, _Float16* __restrict__ BpA,
                                _Float16* __restrict__ BpB, _Float16* __restrict__ Bpb,
                                _Float16* __restrict__ Bpc,
                                _Float16* __restrict__ s1, _Float16* __restrict__ s2,
                                _Float16* __restrict__ s3) {
  int idx = blockIdx.x * blockDim.x + threadIdx.x;
  if (idx < 184320) {                       // Bpb: 5 scales x 18x4x512
    int sc = idx / 36864, rem = idx - sc * 36864;
    pack_generic(rem, 4, 64, 1.f, fWb + sc * 36864, Bpb + sc * 36864);
  } else if (idx < 460800) {                // Bpc: 5 scales x 18x6x512, prescaled by log2e
    int i2 = idx - 184320;
    int sc = i2 / 55296, rem = i2 - sc * 55296;
    pack_generic(rem, 6, 81, LOG2E, fWc + sc * 46656, Bpc + sc * 55296);
  } else if (idx < 471040) {                // Bp1: conv1, K=9 pad 32
    int i2 = idx - 460800;
    int sc = i2 >> 11, rem = i2 & 2047;
    int j = rem & 7, lane = (rem >> 3) & 63, nt = rem >> 9;
    int oc = nt * 16 + (lane & 15);
    int k = ((lane >> 4) & 3) * 8 + j;
    float v = (k < 9) ? fWa[sc * 576 + oc * 9 + k] : 0.f;
    Bp1[sc * 2048 + rem] = (_Float16)v;
  } else if (idx < 475136) {                // BpA: tail stage1, K=45 pad 64
    int rem = idx - 471040;
    int j = rem & 7, lane = (rem >> 3) & 63;
    int nt = (rem >> 9) & 3, s = rem >> 11;
    int oc = nt * 16 + (lane & 15);
    int k = s * 32 + ((lane >> 4) & 3) * 8 + j;
    float v = 0.f;
    if (k < 45) { int ic = k / 9, tap = k - ic * 9; v = W2a[(oc * 5 + ic) * 9 + tap]; }
    BpA[rem] = (_Float16)v;
  } else if (idx < 484352) {                // BpB: tail stage2 (COUT=1, NT=1)
    pack_generic(idx - 475136, 1, 1, 1.f, W2b, BpB);
  } else if (idx < 615424) {                // s1: 512->256, both batches
    int i2 = idx - 484352;
    int n = i2 >> 16, p = i2 & 65535, rr = p >> 8, cc = p & 255;
    s1[i2] = (_Float16)x[(size_t)n * 262144 + (size_t)(rr * 2) * 512 + cc * 2];
  } else if (idx < 648192) {                // s2: 512->128
    int i2 = idx - 615424;
    int n = i2 >> 14, p = i2 & 16383, rr = p >> 7, cc = p & 127;
    s2[i2] = (_Float16)x[(size_t)n * 262144 + (size_t)(rr * 4) * 512 + cc * 4];
  } else if (idx < 656384) {                // s3: 512->64
    int i2 = idx - 648192;
    int n = i2 >> 12, p = i2 & 4095, rr = p >> 6, cc = p & 63;
    s3[i2] = (_Float16)x[(size_t)n * 262144 + (size_t)(rr * 8) * 512 + cc * 8];
  }
}

// ---------------- block -> (scale, batch, tile) mapping, all 5 scales in one grid ----------
// XCD-aware swizzle (r14): each XCD gets a contiguous 596-tile stretch.
__device__ __forceinline__ int xcd_swizzle(int bid) {
  return (bid & 7) * 596 + (bid >> 3);     // 4768 = 8 * 596
}

__device__ __forceinline__ void map_block(int bid, int& sc, int& n, int& bx, int& by,
                                          int& Hs, int& RS, int& h2off) {
  if (bid < 2048) { sc = 0; Hs = 512; RS = 1; h2off = 0;
    int t = bid; n = t >> 10; t &= 1023; by = t >> 5; bx = t & 31; }
  else if (bid < 4096) { sc = 4; Hs = 512; RS = 1; h2off = 33554432;
    int t = bid - 2048; n = t >> 10; t &= 1023; by = t >> 5; bx = t & 31; }
  else if (bid < 4608) { sc = 1; Hs = 256; RS = 2; h2off = 67108864;
    int t = bid - 4096; n = t >> 8; t &= 255; by = t >> 4; bx = t & 15; }
  else if (bid < 4736) { sc = 2; Hs = 128; RS = 4; h2off = 75497472;
    int t = bid - 4608; n = t >> 6; t &= 63; by = t >> 3; bx = t & 7; }
  else { sc = 3; Hs = 64; RS = 8; h2off = 77594624;
    int t = bid - 4736; n = t >> 4; t &= 15; by = t >> 2; bx = t & 3; }
}

__device__ __forceinline__ const void* pick_src(int sc, const float* x, const float* g,
                                                const _Float16* s1, const _Float16* s2,
                                                const _Float16* s3, int& sStr, bool& f16s) {
  if (sc == 0) { sStr = 262144; f16s = false; return x; }
  if (sc == 1) { sStr = 65536; f16s = true; return s1; }
  if (sc == 2) { sStr = 16384; f16s = true; return s2; }
  if (sc == 3) { sStr = 4096; f16s = true; return s3; }
  sStr = 262144; f16s = false; return g;
}

__device__ __forceinline__ float src_load(const void* p, bool f16s, size_t off) {
  return f16s ? (float)((const _Float16*)p)[off] : ((const float*)p)[off];
}

// ============ r20/r21 shared counted-vmcnt tap loop (T3/T4/T5, proven on conv3sd) =========
// slab logical layout: [px = R*18+C][64 ch], 8 slots of 8 ch; physical slot = logical^(C&7).
// B packed s-major (s = tap*2 + half): per tap chunk = 2*NT*64 half8, linear.
// Bsd: double buffer, per buf NT*1024 halves (NT*2048 B).
// Schedule per tap: {stage B(t+1) via NT x gll4/wave; vmcnt(NT); s_barrier; 2x(NT x ds_read
// + MT x ds_read + setprio-wrapped MFMA cluster); lgkmcnt(0); s_barrier}. vmcnt(0) only at
// tap 8. No __syncthreads -> no full pipeline drains inside the loop.
template <int NT>
__device__ __forceinline__ void stageB_tap(const half8* __restrict__ Bp,
                                           _Float16* __restrict__ Bsd,
                                           int t, int buf, int tid) {
  const int lane = tid & 63, wv = tid >> 6;
  const char* s = (const char*)(Bp + (size_t)t * NT * 128) + wv * NT * 256 + lane * 4;
  char* d = (char*)Bsd + (size_t)buf * NT * 2048 + wv * NT * 256;
#pragma unroll
  for (int i = 0; i < NT; ++i) gll4(s + i * 256, d + i * 256);
}

template <int NT>
__device__ __forceinline__ void stageB01(const half8* __restrict__ Bp,
                                         _Float16* __restrict__ Bsd, int tid) {
  stageB_tap<NT>(Bp, Bsd, 0, 0, tid);
  stageB_tap<NT>(Bp, Bsd, 1, 1, tid);
}

template <int MT, int NT, bool SWAP>
__device__ __forceinline__ void tap_loop_counted(const _Float16* __restrict__ slab,
                                                 const half8* __restrict__ Bp,
                                                 _Float16* __restrict__ Bsd,
                                                 f32x4 (&acc)[MT][NT], int tid) {
  const int lane = tid & 63;
  const int wv = tid >> 6;
  const int quad = lane >> 4;
  const int ln15 = lane & 15;
  auto tap_body = [&](int t, int buf) {
    const int dy = t / 3, dx = t - dy * 3;
    const int C = dx + ln15;
    const int cx = C & 7;
    const _Float16* bb = Bsd + (size_t)buf * NT * 1024;
#pragma unroll
    for (int h = 0; h < 2; ++h) {
      half8 bf[NT];
#pragma unroll
      for (int nt = 0; nt < NT; ++nt)
        bf[nt] = *(const half8*)(bb + h * NT * 512 + (nt * 64 + lane) * 8);
      half8 af[MT];
#pragma unroll
      for (int mt = 0; mt < MT; ++mt) {
        const int px = (wv * MT + mt + dy) * 18 + C;
        af[mt] = *(const half8*)(slab + (size_t)px * 64 + ((h * 4 + quad) ^ cx) * 8);
      }
      __builtin_amdgcn_s_setprio(1);
#pragma unroll
      for (int mt = 0; mt < MT; ++mt)
#pragma unroll
        for (int nt = 0; nt < NT; ++nt)
          acc[mt][nt] = SWAP
            ? __builtin_amdgcn_mfma_f32_16x16x32_f16(bf[nt], af[mt], acc[mt][nt], 0, 0, 0)
            : __builtin_amdgcn_mfma_f32_16x16x32_f16(af[mt], bf[nt], acc[mt][nt], 0, 0, 0);
      __builtin_amdgcn_s_setprio(0);
    }
  };
#pragma unroll 1
  for (int t = 0; t < 8; ++t) {
    if (t >= 1) stageB_tap<NT>(Bp, Bsd, t + 1, (t + 1) & 1, tid);  // buf safe: BAR_b(t-1)
    asm volatile("s_waitcnt vmcnt(%0)" :: "n"(NT) : "memory");     // B(t) landed; B(t+1) flies
    __builtin_amdgcn_s_barrier();                                  // BAR_a
    asm volatile("" ::: "memory");
    tap_body(t, t & 1);
    asm volatile("s_waitcnt lgkmcnt(0)" ::: "memory");             // my buf reads retired
    __builtin_amdgcn_s_barrier();                                  // BAR_b
    asm volatile("" ::: "memory");
  }
  asm volatile("s_waitcnt vmcnt(0)" ::: "memory");
  __builtin_amdgcn_s_barrier();
  asm volatile("" ::: "memory");
  tap_body(8, 0);
}

// K-loop + global-store epilogue (unswapped; px-major for write combining).
// Caller must have issued stageB01<NT> and fully drained LDS/VMEM (e.g. __syncthreads)
// before calling (so the tap loop's vmcnt ledger starts clean).
template <int MT, int NT, int COUT, int COUTP, bool RELU, typename OutT>
__device__ __forceinline__ void mfma_body(const _Float16* slab, const half8* __restrict__ Bp,
                                          _Float16* __restrict__ Bsd,
                                          const float* __restrict__ bias,
                                          OutT* __restrict__ out,
                                          int H, int W, int gr0, int gc0, int tid) {
  f32x4 acc[MT][NT];
  const f32x4 zz = {0.f, 0.f, 0.f, 0.f};
#pragma unroll
  for (int mt = 0; mt < MT; ++mt)
#pragma unroll
    for (int nt = 0; nt < NT; ++nt) acc[mt][nt] = zz;
  tap_loop_counted<MT, NT, false>(slab, Bp, Bsd, acc, tid);
  const int lane = tid & 63;
  const int wv = tid >> 6;
  const int quad = lane >> 4;
  const int ln15 = lane & 15;
  float bvv[NT];
#pragma unroll
  for (int nt = 0; nt < NT; ++nt) {
    const int oc = nt * 16 + ln15;
    bvv[nt] = (oc < COUT) ? bias[oc] : 0.f;
  }
#pragma unroll
  for (int mt = 0; mt < MT; ++mt) {
    const int gr = gr0 + wv * MT + mt;
#pragma unroll
    for (int reg = 0; reg < 4; ++reg) {
      const int gc = gc0 + quad * 4 + reg;
#pragma unroll
      for (int nt = 0; nt < NT; ++nt) {
        const int oc = nt * 16 + ln15;
        float v = acc[mt][nt][reg] + bvv[nt];
        if (RELU) v = fmaxf(v, 0.f);
        if (oc < COUTP) out[((size_t)gr * W + gc) * COUTP + oc] = (OutT)v;
      }
    }
  }
}

// ---------------- all-scale fused conv1+conv2 (MFMA), single dispatch ----------------------
// r21: conv2 K-loop on the counted-vmcnt template.
__global__ __launch_bounds__(512, 4)
void conv12_ms_kernel(const float* __restrict__ x, const float* __restrict__ g,
                      const _Float16* __restrict__ s1, const _Float16* __restrict__ s2,
                      const _Float16* __restrict__ s3,
                      const half8* __restrict__ Bp1b, const float* __restrict__ fba,
                      const half8* __restrict__ Bpbb, const float* __restrict__ fbb,
                      _Float16* __restrict__ h2) {
  __shared__ float xs[20 * 20];                         // first: gather clamps stay inside
  __shared__ __align__(16) _Float16 slab[18 * 18 * 64];
  __shared__ __align__(16) _Float16 BsS[2 * 4096];      // 16 KB B double-buffer (NT=4)
  int sc, n, bx, by, Hs, RS, h2off;
  map_block(xcd_swizzle(blockIdx.x), sc, n, bx, by, Hs, RS, h2off);
  int sStr; bool f16s;
  const void* src = pick_src(sc, x, g, s1, s2, s3, sStr, f16s);
  _Float16* out = h2 + h2off + (size_t)n * Hs * Hs * 64;
  const half8* Bp1 = Bp1b + sc * 256;
  const half8* Bp = Bpbb + sc * 4608;
  const float* ba = fba + sc * 64;
  const float* bb = fbb + sc * 64;
  const int H = Hs, W = Hs;
  const int tid = threadIdx.x;
  const int gr0 = by * 16, gc0 = bx * 16;
  stageB01<4>(Bp, BsS, tid);            // issue early; drained by the pre-conv2 __syncthreads
  for (int i = tid; i < 400; i += 512) {
    int R = i / 20, C = i % 20;
    int gr = gr0 - 2 + R, gc = gc0 - 2 + C;
    xs[i] = (gr >= 0 && gr < H && gc >= 0 && gc < W)
                ? src_load(src, f16s, (size_t)n * sStr + (size_t)gr * W + gc) : 0.f;
  }
  __syncthreads();
  const int lane = tid & 63;
  const int wv = tid >> 6;
  const int quad = lane >> 4;
  const int ln15 = lane & 15;
  half8 bf1[4];
  float b1v[4][4];
#pragma unroll
  for (int nt = 0; nt < 4; ++nt) {
    bf1[nt] = Bp1[nt * 64 + lane];
#pragma unroll
    for (int reg = 0; reg < 4; ++reg) b1v[nt][reg] = ba[nt * 16 + quad * 4 + reg];
  }
  int off1[8];
  bool v1[8];
#pragma unroll
  for (int j = 0; j < 8; ++j) {
    int k = quad * 8 + j;
    v1[j] = (k < 9);
    off1[j] = v1[j] ? ((k / 3) * 20 + (k % 3)) : 0;
  }
  const f32x4 zz = {0.f, 0.f, 0.f, 0.f};
#pragma unroll 1
  for (int mt = wv; mt < 21; mt += 8) {
    int p = mt * 16 + ln15;
    int pcl = (p < 323) ? p : 323;
    int Rg = pcl / 18, Cg = pcl - Rg * 18;
    int base = Rg * 20 + Cg;
    half8 af;
#pragma unroll
    for (int j = 0; j < 8; ++j)
      af[j] = v1[j] ? (_Float16)xs[base + off1[j]] : (_Float16)0.f;
    f32x4 a1[4] = {zz, zz, zz, zz};
#pragma unroll
    for (int nt = 0; nt < 4; ++nt)
      a1[nt] = __builtin_amdgcn_mfma_f32_16x16x32_f16(bf1[nt], af, a1[nt], 0, 0, 0);
    if (p < 324) {
      int R2 = p / 18, C2 = p - R2 * 18;
      int gr = gr0 - 1 + R2, gc = gc0 - 1 + C2;
      bool inb = (gr >= 0 && gr < H && gc >= 0 && gc < W);
      _Float16* sb = slab + p * 64 + (quad & 1) * 4;
      const int csw = C2 & 7;
#pragma unroll
      for (int nt = 0; nt < 4; ++nt) {
        half4v w;
#pragma unroll
        for (int reg = 0; reg < 4; ++reg) {
          float v = inb ? fmaxf(a1[nt][reg] + b1v[nt][reg], 0.f) : 0.f;
          w[reg] = (_Float16)v;
        }
        const int chunk = nt * 2 + (quad >> 1);
        *(half4v*)(sb + ((chunk ^ csw) * 8)) = w;
      }
    }
  }
  __syncthreads();                      // slab ready; drains vmcnt (B0/B1 landed long ago)
  mfma_body<2, 4, 64, 64, true, _Float16>(slab, Bp, BsS, bb, out, H, W, gr0, gc0, tid);
}

// ---------------- all-scale fused conv3 + softmax + dynconv + upsample ---------------------
// r20-proven counted pipeline on the shared template.
__global__ __launch_bounds__(512, 2)
void conv3sd_ms_kernel(const _Float16* __restrict__ h2, const half8* __restrict__ Bpcb,
                       const float* __restrict__ fbc,
                       const float* __restrict__ x, const float* __restrict__ g,
                       const _Float16* __restrict__ s1, const _Float16* __restrict__ s2,
                       const _Float16* __restrict__ s3, float* __restrict__ cat) {
  __shared__ __align__(16) _Float16 slab[384 * 64];     // 49152 B
  __shared__ __align__(16) _Float16 Bsd[2 * 6144];      // 24576 B (NT=6)
  __shared__ float xs[24 * 24];
  int sc, n, bx, by, Hs, RS, h2off;
  map_block(xcd_swizzle(blockIdx.x), sc, n, bx, by, Hs, RS, h2off);
  int sStr; bool f16s;
  const void* src = pick_src(sc, x, g, s1, s2, s3, sStr, f16s);
  const _Float16* in = h2 + h2off + (size_t)n * Hs * Hs * 64;
  const half8* Bp = Bpcb + sc * 6912;
  const float* bias = fbc + sc * 81;
  float* catp = cat + (size_t)(sc * 2 + n) * 262144;
  const int H = Hs, W = Hs;
  const int tid = threadIdx.x;
  const int gr0 = by * 16, gc0 = bx * 16;
  const int lane = tid & 63;
  const int wv = tid >> 6;
  const int quad = lane >> 4;
  const int ln15 = lane & 15;

  // xs (dynconv input tile) — plain staging, consumed after the loop
  for (int i = tid; i < 576; i += 512) {
    int R = i / 24, C = i % 24;
    int gr = gr0 - 4 + R, gc = gc0 - 4 + C;
    xs[i] = (gr >= 0 && gr < H && gc >= 0 && gc < W)
                ? src_load(src, f16s, (size_t)n * sStr + (size_t)gr * W + gc) : 0.f;
  }

  // ---- slab staging (once, both halves) ----
  const bool interior = (gr0 > 0) && (gc0 > 0) && (gr0 + 17 <= H) && (gc0 + 17 <= W);
  if (interior) {
    const int pxb0 = wv * 48;                 // 48 px per wave; 8 px per gll16
#pragma unroll
    for (int k = 0; k < 6; ++k) {
      const int pxb = pxb0 + k * 8;
      int px = pxb + (lane >> 3);
      int pcl = (px < 324) ? px : 323;        // pad px read valid-but-unused memory
      int R = pcl / 18, C = pcl - R * 18;
      int l = (lane & 7) ^ (C & 7);           // source-side swizzle (rule #21)
      gll16((const char*)(in + ((size_t)(gr0 - 1 + R) * W + (gc0 - 1 + C)) * 64 + l * 8),
            (char*)slab + (size_t)pxb * 128);
    }
  } else {
    for (int i = tid; i < 2592; i += 512) {   // 324 px x 8 slots, reg-staged, same layout
      int px = i >> 3, pslot = i & 7;
      int R = px / 18, C = px - R * 18;
      int gr = gr0 - 1 + R, gc = gc0 - 1 + C;
      int l = pslot ^ (C & 7);
      half8 v = {0, 0, 0, 0, 0, 0, 0, 0};
      if (gr >= 0 && gr < H && gc >= 0 && gc < W)
        v = *(const half8*)(in + ((size_t)gr * W + gc) * 64 + l * 8);
      *(half8*)(slab + (size_t)px * 64 + pslot * 8) = v;
    }
  }

  stageB01<6>(Bp, Bsd, tid);
  asm volatile("s_waitcnt lgkmcnt(0)" ::: "memory");    // edge-path ds_writes + xs drained

  f32x4 acc[2][6];
  const f32x4 zz = {0.f, 0.f, 0.f, 0.f};
#pragma unroll
  for (int mt = 0; mt < 2; ++mt)
#pragma unroll
    for (int nt = 0; nt < 6; ++nt) acc[mt][nt] = zz;
  tap_loop_counted<2, 6, true>(slab, Bp, Bsd, acc, tid);

  // ---- softmax + dynconv + upsample epilogue (r10-verified, MT=2) ----
  float bvv[6][4];
  int dyx[6][4];
  bool vv[6][4];
#pragma unroll
  for (int nt = 0; nt < 6; ++nt)
#pragma unroll
    for (int reg = 0; reg < 4; ++reg) {
      int ch = nt * 16 + quad * 4 + reg;
      bool ok = (ch < 81);
      vv[nt][reg] = ok;
      bvv[nt][reg] = ok ? bias[ch] * LOG2E : 0.f;
      int dy = ch / 9, dx = ch - dy * 9;
      dyx[nt][reg] = ok ? dy * 24 + dx : 0;
    }
  const int lrs = (RS == 2) ? 1 : ((RS == 4) ? 2 : 3);
#pragma unroll
  for (int mt = 0; mt < 2; ++mt) {
    const float* xb = xs + (wv * 2 + mt) * 24 + ln15;
    float sum = 0.f, y = 0.f;
#pragma unroll
    for (int nt = 0; nt < 6; ++nt)
#pragma unroll
      for (int reg = 0; reg < 4; ++reg) {
        if (vv[nt][reg]) {
          float e = exp2f(acc[mt][nt][reg] + bvv[nt][reg]);
          sum += e;
          y = fmaf(e, xb[dyx[nt][reg]], y);
        }
      }
    sum += __shfl_xor(sum, 16, 64);
    sum += __shfl_xor(sum, 32, 64);
    y += __shfl_xor(y, 16, 64);
    y += __shfl_xor(y, 32, 64);
    const float o = y / sum;
    const int gr = gr0 + wv * 2 + mt, gc = gc0 + ln15;
    if (RS == 1) {
      if (quad == 0) catp[(size_t)gr * 512 + gc] = o;
    } else {
      for (int t = quad; t < RS * RS; t += 4) {
        int a = t >> lrs, b = t & (RS - 1);
        catp[((size_t)(gr * RS + a)) * 512 + (gc * RS + b)] = o;
      }
    }
  }
}

// ---------------- fused tail: cat(5 planes) -> MFMA 5->64 relu (LDS) -> MFMA 64->1 ---------
// r21: stage2 K-loop on the counted-vmcnt template.
__global__ __launch_bounds__(512, 4)
void tail_fused_kernel(const float* __restrict__ cat,
                       const half8* __restrict__ BpA, const float* __restrict__ b2a,
                       const half8* __restrict__ BpB, const float* __restrict__ b2b,
                       float* __restrict__ out) {
  __shared__ float cs[20 * 20 * 5];                      // first: gather clamps stay inside
  __shared__ __align__(16) _Float16 hid[18 * 18 * 64];
  __shared__ __align__(16) _Float16 BsS[2 * 1024];       // 4 KB B double-buffer (NT=1)
  const int n = blockIdx.z;
  float* op = out + (size_t)n * (512 * 512);
  const int tid = threadIdx.x;
  const int gr0 = blockIdx.y * 16, gc0 = blockIdx.x * 16;
  stageB01<1>(BpB, BsS, tid);           // issue early; drained by the pre-stage2 __syncthreads
  for (int i = tid; i < 2000; i += 512) {
    int ic = i / 400, px = i - ic * 400;
    int R = px / 20, C = px - R * 20;
    int gr = gr0 - 2 + R, gc = gc0 - 2 + C;
    cs[px * 5 + ic] = (gr >= 0 && gr < 512 && gc >= 0 && gc < 512)
                ? cat[(size_t)(ic * 2 + n) * 262144 + (size_t)gr * 512 + gc] : 0.f;
  }
  __syncthreads();
  const int lane = tid & 63;
  const int wv = tid >> 6;
  const int quad = lane >> 4;
  const int ln15 = lane & 15;
  int goff[2][8];
  bool gok[2][8];
#pragma unroll
  for (int s = 0; s < 2; ++s)
#pragma unroll
    for (int j = 0; j < 8; ++j) {
      int k = s * 32 + quad * 8 + j;
      bool ok = (k < 45);
      int ic = k / 9;
      int tap = k - ic * 9;
      int dy = tap / 3, dx = tap - dy * 3;
      goff[s][j] = ok ? ((dy * 20 + dx) * 5 + ic) : 0;
      gok[s][j] = ok;
    }
  half8 bfA[2][4];
  float bAv[4][4];
#pragma unroll
  for (int s = 0; s < 2; ++s)
#pragma unroll
    for (int nt = 0; nt < 4; ++nt) bfA[s][nt] = BpA[(s * 4 + nt) * 64 + lane];
#pragma unroll
  for (int nt = 0; nt < 4; ++nt)
#pragma unroll
    for (int reg = 0; reg < 4; ++reg) bAv[nt][reg] = b2a[nt * 16 + quad * 4 + reg];
  const f32x4 zz = {0.f, 0.f, 0.f, 0.f};
#pragma unroll 1
  for (int mt = wv; mt < 21; mt += 8) {
    int p = mt * 16 + ln15;
    int pcl = (p < 323) ? p : 323;
    int base = (pcl / 18) * 100 + (pcl % 18) * 5;
    f32x4 acc1[4] = {zz, zz, zz, zz};
#pragma unroll
    for (int s = 0; s < 2; ++s) {
      half8 af;
#pragma unroll
      for (int j = 0; j < 8; ++j) {
        float a = gok[s][j] ? cs[base + goff[s][j]] : 0.f;
        af[j] = (_Float16)a;
      }
#pragma unroll
      for (int nt = 0; nt < 4; ++nt)
        acc1[nt] = __builtin_amdgcn_mfma_f32_16x16x32_f16(bfA[s][nt], af, acc1[nt], 0, 0, 0);
    }
    if (p < 324) {
      int R2 = p / 18, C2 = p - R2 * 18;
      int gr = gr0 - 1 + R2, gc = gc0 - 1 + C2;
      bool inb = (gr >= 0 && gr < 512 && gc >= 0 && gc < 512);
      _Float16* sb = hid + p * 64 + (quad & 1) * 4;
      const int csw = C2 & 7;
#pragma unroll
      for (int nt = 0; nt < 4; ++nt) {
        half4v w;
#pragma unroll
        for (int reg = 0; reg < 4; ++reg) {
          float v = inb ? fmaxf(acc1[nt][reg] + bAv[nt][reg], 0.f) : 0.f;
          w[reg] = (_Float16)v;
        }
        const int chunk = nt * 2 + (quad >> 1);
        *(half4v*)(sb + ((chunk ^ csw) * 8)) = w;
      }
    }
  }
  __syncthreads();                      // hid ready; drains vmcnt (B0/B1 landed long ago)
  mfma_body<2, 1, 1, 1, false, float>(hid, BpB, BsS, b2b, op, 512, 512, gr0, gc0, tid);
}

extern "C" void kernel_launch(void* const* d_in, const int* in_sizes, int n_in,
                              void* d_out, int out_size, void* d_ws, size_t ws_size,
                              hipStream_t stream) {
  (void)in_sizes; (void)n_in; (void)out_size; (void)ws_size;
  const float* x   = (const float*)d_in[0];
  const float* g   = (const float*)d_in[1];
  const float* fWa = (const float*)d_in[2];
  const float* fba = (const float*)d_in[3];
  const float* fWb = (const float*)d_in[4];
  const float* fbb = (const float*)d_in[5];
  const float* fWc = (const float*)d_in[6];
  const float* fbc = (const float*)d_in[7];
  const float* W2a = (const float*)d_in[8];
  const float* b2a = (const float*)d_in[9];
  const float* W2b = (const float*)d_in[10];
  const float* b2b = (const float*)d_in[11];
  float* out = (float*)d_out;
  float* ws = (float*)d_ws;

  // carve (float units), total 42,009,088 floats = 168.04 MB
  float* Bp1F = ws;                     // 5120
  float* BpAF = Bp1F + 5120;            // 2048
  float* BpBF = BpAF + 2048;            // 4608
  float* BpbF = BpBF + 4608;            // 92160
  float* BpcF = BpbF + 92160;           // 138240
  float* s1F  = BpcF + 138240;          // 65536
  float* s2F  = s1F + 65536;            // 16384
  float* s3F  = s2F + 16384;            // 4096
  float* cat  = s3F + 4096;             // 2621440 (10 planes of 262144)
  float* h2F  = cat + 2621440;          // 39,059,456
  _Float16* s1 = (_Float16*)s1F;
  _Float16* s2 = (_Float16*)s2F;
  _Float16* s3 = (_Float16*)s3F;
  _Float16* h2 = (_Float16*)h2F;
  const half8* Bp1 = (const half8*)Bp1F;
  const half8* BpA = (const half8*)BpAF;
  const half8* BpB = (const half8*)BpBF;
  const half8* Bpb = (const half8*)BpbF;
  const half8* Bpc = (const half8*)BpcF;

  prep_all_kernel<<<2564, 256, 0, stream>>>(fWa, fWb, fWc, W2a, W2b, x,
                                            (_Float16*)Bp1F, (_Float16*)BpAF,
                                            (_Float16*)BpBF, (_Float16*)BpbF,
                                            (_Float16*)BpcF, s1, s2, s3);
  conv12_ms_kernel<<<4768, 512, 0, stream>>>(x, g, s1, s2, s3, Bp1, fba, Bpb, fbb, h2);
  conv3sd_ms_kernel<<<4768, 512, 0, stream>>>(h2, Bpc, fbc, x, g, s1, s2, s3, cat);
  tail_fused_kernel<<<dim3(32, 32, 2), 512, 0, stream>>>(cat, BpA, b2a, BpB, b2b, out);
}